// Round 4
// baseline (519.313 us; speedup 1.0000x reference)
//
#include <hip/hip_runtime.h>

typedef _Float16 f16;
typedef _Float16 f16x8 __attribute__((ext_vector_type(8)));
typedef float    f32x4 __attribute__((ext_vector_type(4)));

#define V  32000
#define E  128
#define H  128
#define B  32
#define T  128
#define G3 384   // 3H

// ---------- K0: fc_w (256,V) f32  ->  Bt16 (V,256) f16 (transposed, converted)
__global__ __launch_bounds__(256) void k0_convert_fcw(const float* __restrict__ fc_w,
                                                      f16* __restrict__ Bt16)
{
    int v  = blockIdx.x * 256 + threadIdx.x;   // 0..31999, coalesced across lanes
    int k0 = blockIdx.y * 64;
    for (int kk = 0; kk < 64; kk += 8) {
        f16x8 p;
        #pragma unroll
        for (int e = 0; e < 8; ++e)
            p[e] = (f16)fc_w[(size_t)(k0 + kk + e) * V + v];
        *(f16x8*)(Bt16 + (size_t)v * 256 + (k0 + kk)) = p;
    }
}

// ---------- K1: xg = embedding[x] @ W_ih + b    (B*T, 3H)
__global__ __launch_bounds__(384) void k1_embed_xg(const int* __restrict__ x,
                                                   const float* __restrict__ emb,
                                                   const float* __restrict__ W_ih,
                                                   const float* __restrict__ bias,
                                                   float* __restrict__ xg)
{
    int j = threadIdx.x;
    float w[E];
    #pragma unroll
    for (int k = 0; k < E; ++k) w[k] = W_ih[k * G3 + j];
    float bj = bias[j];

    __shared__ __align__(16) float erow[16][E];
    int row0 = blockIdx.x * 16;
    for (int i = j; i < 16 * E; i += G3) {
        int r = i >> 7, c = i & (E - 1);
        erow[r][c] = emb[(size_t)x[row0 + r] * E + c];
    }
    __syncthreads();
    for (int r = 0; r < 16; ++r) {
        float acc = bj;
        #pragma unroll
        for (int k = 0; k < E; k += 4) {
            f32x4 hv = *(const f32x4*)&erow[r][k];
            acc += hv[0]*w[k] + hv[1]*w[k+1] + hv[2]*w[k+2] + hv[3]*w[k+3];
        }
        xg[(size_t)(row0 + r) * G3 + j] = acc;
    }
}

// ---------- K2: GRU scan. One block per batch; W_hh column j in registers of thread j.
__global__ __launch_bounds__(384) void k2_gru(const float* __restrict__ xg,
                                              const float* __restrict__ W_hh,
                                              float* __restrict__ hs,
                                              f16* __restrict__ A16)
{
    int b = blockIdx.x;
    int j = threadIdx.x;
    float w[H];
    #pragma unroll
    for (int k = 0; k < H; ++k) w[k] = W_hh[k * G3 + j];

    __shared__ __align__(16) float h[H];
    __shared__ float g[G3];
    if (j < H) h[j] = 0.0f;
    __syncthreads();

    const float* xgb = xg + (size_t)b * T * G3;
    float xnext = xgb[j];
    for (int t = 0; t < T; ++t) {
        float acc = xnext;
        if (t + 1 < T) xnext = xgb[(size_t)(t + 1) * G3 + j];  // prefetch next step
        #pragma unroll
        for (int k = 0; k < H; k += 4) {
            f32x4 hv = *(const f32x4*)&h[k];
            acc += hv[0]*w[k] + hv[1]*w[k+1] + hv[2]*w[k+2] + hv[3]*w[k+3];
        }
        g[j] = acc;
        __syncthreads();
        if (j < H) {
            float z  = 1.0f / (1.0f + __expf(-g[j]));
            float r  = 1.0f / (1.0f + __expf(-g[H + j]));
            float pn = g[2 * H + j] * r;
            float ex = __expf(2.0f * pn);
            float n  = 1.0f - 2.0f / (ex + 1.0f);      // tanh(pn)
            float hn = (1.0f - z) * n + z * h[j];
            h[j] = hn;
            size_t bt = (size_t)b * T + t;
            hs[bt * H + j] = hn;
            A16[bt * 256 + j] = (f16)hn;               // first half of combined
        }
        __syncthreads();
    }
}

// ---------- K3: scores = tanh(hs @ attn_w + attn_b) @ v_w + v_b   (B*T,)
__global__ __launch_bounds__(128) void k3_scores(const float* __restrict__ hs,
                                                 const float* __restrict__ attn_w,
                                                 const float* __restrict__ attn_b,
                                                 const float* __restrict__ v_w,
                                                 const float* __restrict__ v_b,
                                                 float* __restrict__ scores)
{
    int i = threadIdx.x;
    float w[H];
    #pragma unroll
    for (int k = 0; k < H; ++k) w[k] = attn_w[k * H + i];
    float ab = attn_b[i];
    float vw = v_w[i];
    float vb = v_b[0];

    __shared__ __align__(16) float hrow[H];
    __shared__ float part[2];
    int row0 = blockIdx.x * 16;
    for (int r = 0; r < 16; ++r) {
        hrow[i] = hs[(size_t)(row0 + r) * H + i];
        __syncthreads();
        float acc = ab;
        #pragma unroll
        for (int k = 0; k < H; k += 4) {
            f32x4 hv = *(const f32x4*)&hrow[k];
            acc += hv[0]*w[k] + hv[1]*w[k+1] + hv[2]*w[k+2] + hv[3]*w[k+3];
        }
        float ex = __expf(2.0f * acc);
        float u  = (1.0f - 2.0f / (ex + 1.0f)) * vw;   // tanh(acc)*v_w[i]
        #pragma unroll
        for (int o = 32; o > 0; o >>= 1) u += __shfl_xor(u, o);
        if ((i & 63) == 0) part[i >> 6] = u;
        __syncthreads();
        if (i == 0) scores[row0 + r] = part[0] + part[1] + vb;
        __syncthreads();
    }
}

// ---------- K4: causal softmax over scores[s<t] and context; writes second half of A16.
__global__ __launch_bounds__(128) void k4_context(const float* __restrict__ hs,
                                                  const float* __restrict__ scores,
                                                  f16* __restrict__ A16)
{
    int bt = blockIdx.x;
    int b  = bt >> 7;
    int t  = bt & (T - 1);
    int i  = threadIdx.x;

    __shared__ float wts[T];
    __shared__ float redm[2], reds[2];
    const float* sc = scores + b * T;

    float sv = (i < t) ? sc[i] : -3.0e38f;
    float m = sv;
    #pragma unroll
    for (int o = 32; o > 0; o >>= 1) m = fmaxf(m, __shfl_xor(m, o));
    if ((i & 63) == 0) redm[i >> 6] = m;
    __syncthreads();
    m = fmaxf(redm[0], redm[1]);

    float ev = (i < t) ? __expf(sc[i] - m) : 0.0f;
    float s = ev;
    #pragma unroll
    for (int o = 32; o > 0; o >>= 1) s += __shfl_xor(s, o);
    if ((i & 63) == 0) reds[i >> 6] = s;
    __syncthreads();
    s = reds[0] + reds[1];

    float inv = (t > 0) ? 1.0f / s : 0.0f;   // t==0 -> context 0
    wts[i] = ev * inv;
    __syncthreads();

    float ctx = 0.0f;
    const float* hsb = hs + (size_t)b * T * H + i;
    for (int sI = 0; sI < t; ++sI)
        ctx = fmaf(wts[sI], hsb[(size_t)sI * H], ctx);

    A16[(size_t)bt * 256 + H + i] = (f16)ctx;
}

// ---------- K5: out = combined(4096x256) @ fc_w(256xV) + fc_b   via fp16 MFMA.
// B-tile (64KB) in LDS once per block (250 blocks, one per 128-col N-tile).
// Epilogue: per-wave LDS transpose (8KB each) so each global store writes two
// 512B fully-contiguous full-line segments; stores NONTEMPORAL so the write
// stream does not evict A16/Bt16 from L2/L3 (keeps A reads cache-resident).
__global__ __launch_bounds__(512, 2) void k5_gemm(const f16* __restrict__ A16,
                                                  const f16* __restrict__ Bt16,
                                                  const float* __restrict__ fc_b,
                                                  float* __restrict__ out)
{
    __shared__ __align__(16) char Bs[65536];   // B tile: [128 n][512 B k], XOR-swizzled
    __shared__ __align__(16) char Tb[65536];   // 8 waves x 8KB transpose buffers
    int nt   = blockIdx.x;           // 0..249
    int tid  = threadIdx.x;
    int w    = tid >> 6;             // wave 0..7
    int lane = tid & 63;
    int l15  = lane & 15;
    int lhi  = lane >> 4;            // 0..3
    int l31  = lane & 31;
    int lh2  = lane >> 5;            // 0..1

    // ---- stage B tile: LDS[lin] = G[row][col ^ ((row&7)<<4)]
    const char* src = (const char*)(Bt16 + (size_t)nt * 128 * 256);
    #pragma unroll
    for (int it = 0; it < 8; ++it) {
        int chunk = it * 8 + w;                  // 1KB chunk
        int lin   = chunk * 1024 + lane * 16;
        int row   = lin >> 9;
        int g     = lin ^ ((row & 7) << 4);
        __builtin_amdgcn_global_load_lds(
            (const __attribute__((address_space(1))) void*)(src + g),
            (__attribute__((address_space(3))) void*)(Bs + chunk * 1024),
            16, 0, 0);
    }

    // bias for this lane's store columns (col = nt*128 + l31*4 + 0..3)
    f32x4 biasT = *(const f32x4*)(fc_b + nt * 128 + l31 * 4);
    char* tw = Tb + w * 8192;        // per-wave transpose buffer: [16 rows][512 B]

    asm volatile("s_waitcnt vmcnt(0)");
    __syncthreads();

    // ---- loop over M: each iter covers 256 rows (8 waves x 32 rows)
    for (int mi = 0; mi < 16; ++mi) {
        int rbase = mi * 256 + w * 32;

        // A fragments from global (cache-resident): lane holds A[rbase+mf*16+l15][k]
        const f16* Ab = A16 + (size_t)(rbase + l15) * 256 + lhi * 8;
        f16x8 a[2][8];
        #pragma unroll
        for (int mf = 0; mf < 2; ++mf)
            #pragma unroll
            for (int kt = 0; kt < 8; ++kt)
                a[mf][kt] = *(const f16x8*)(Ab + mf * 16 * 256 + kt * 32);

        f32x4 acc[2][8];
        #pragma unroll
        for (int mf = 0; mf < 2; ++mf)
            #pragma unroll
            for (int f = 0; f < 8; ++f)
                acc[mf][f] = (f32x4){0.f, 0.f, 0.f, 0.f};

        #pragma unroll
        for (int kt = 0; kt < 8; ++kt) {
            f16x8 bf[8];
            #pragma unroll
            for (int f = 0; f < 8; ++f) {
                int r  = f * 16 + l15;
                int cb = kt * 64 + lhi * 16;               // byte col
                int ad = r * 512 + (cb ^ ((r & 7) << 4));  // swizzled read
                bf[f] = *(const f16x8*)(Bs + ad);
            }
            #pragma unroll
            for (int mf = 0; mf < 2; ++mf)
                #pragma unroll
                for (int f = 0; f < 8; ++f)
                    acc[mf][f] = __builtin_amdgcn_mfma_f32_16x16x32_f16(bf[f], a[mf][kt], acc[mf][f], 0, 0, 0);
        }

        // ---- epilogue: per-wave LDS transpose -> contiguous 512B row segments
        #pragma unroll
        for (int mf = 0; mf < 2; ++mf) {
            // scatter acc into transpose buf: buf[row=l15][colbyte = f*64+lhi*16]
            #pragma unroll
            for (int f = 0; f < 8; ++f) {
                int ad = l15 * 512 + ((f * 64 + lhi * 16) ^ ((l15 & 7) << 4));
                *(f32x4*)(tw + ad) = acc[mf][f];
            }
            // gather rows: lane covers row R = g*2+lh2, cols l31*4..+3 (contiguous)
            #pragma unroll
            for (int g = 0; g < 8; ++g) {
                int R  = g * 2 + lh2;
                int ad = R * 512 + ((l31 * 16) ^ ((R & 7) << 4));
                f32x4 vres = *(const f32x4*)(tw + ad) + biasT;
                int row = rbase + mf * 16 + R;
                __builtin_nontemporal_store(vres,
                    (f32x4*)(out + (size_t)row * V + nt * 128 + l31 * 4));
            }
        }
    }
}

extern "C" void kernel_launch(void* const* d_in, const int* in_sizes, int n_in,
                              void* d_out, int out_size, void* d_ws, size_t ws_size,
                              hipStream_t stream)
{
    (void)in_sizes; (void)n_in; (void)out_size; (void)ws_size;
    const int*   x      = (const int*)  d_in[0];
    const float* emb    = (const float*)d_in[1];
    const float* W_ih   = (const float*)d_in[2];
    const float* W_hh   = (const float*)d_in[3];
    const float* bias   = (const float*)d_in[4];
    const float* attn_w = (const float*)d_in[5];
    const float* attn_b = (const float*)d_in[6];
    const float* v_w    = (const float*)d_in[7];
    const float* v_b    = (const float*)d_in[8];
    const float* fc_w   = (const float*)d_in[9];
    const float* fc_b   = (const float*)d_in[10];
    float* out = (float*)d_out;

    char* ws = (char*)d_ws;
    float* xg     = (float*)(ws);              // 4096*384*4 = 6,291,456 B
    float* hs     = (float*)(ws + 6291456);    // 4096*128*4 = 2,097,152 B
    float* scores = (float*)(ws + 8388608);    // 4096*4     = 16,384 B
    f16*   A16    = (f16*)  (ws + 8404992);    // 4096*256*2 = 2,097,152 B
    f16*   Bt16   = (f16*)  (ws + 10502144);   // 32000*256*2 = 16,384,000 B

    hipLaunchKernelGGL(k0_convert_fcw, dim3(V / 256, 4), dim3(256), 0, stream, fc_w, Bt16);
    hipLaunchKernelGGL(k1_embed_xg,    dim3(B * T / 16), dim3(G3),  0, stream, x, emb, W_ih, bias, xg);
    hipLaunchKernelGGL(k2_gru,         dim3(B),          dim3(G3),  0, stream, xg, W_hh, hs, A16);
    hipLaunchKernelGGL(k3_scores,      dim3(B * T / 16), dim3(H),   0, stream, hs, attn_w, attn_b, v_w, v_b, scores);
    hipLaunchKernelGGL(k4_context,     dim3(B * T),      dim3(H),   0, stream, hs, scores, A16);
    hipLaunchKernelGGL(k5_gemm,        dim3(250),        dim3(512), 0, stream, A16, Bt16, fc_b, out);
}

// Round 5
// 376.922 us; speedup vs baseline: 1.3778x; 1.3778x over previous
//
#include <hip/hip_runtime.h>

typedef _Float16 f16;
typedef _Float16 f16x8 __attribute__((ext_vector_type(8)));
typedef float    f32x4 __attribute__((ext_vector_type(4)));

#define V  32000
#define E  128
#define H  128
#define B  32
#define T  128
#define G3 384   // 3H

// ---------- K0: fc_w (256,V) f32  ->  Bt16 (V,256) f16 (transposed, converted)
__global__ __launch_bounds__(256) void k0_convert_fcw(const float* __restrict__ fc_w,
                                                      f16* __restrict__ Bt16)
{
    int v  = blockIdx.x * 256 + threadIdx.x;   // 0..31999, coalesced across lanes
    int k0 = blockIdx.y * 64;
    for (int kk = 0; kk < 64; kk += 8) {
        f16x8 p;
        #pragma unroll
        for (int e = 0; e < 8; ++e)
            p[e] = (f16)fc_w[(size_t)(k0 + kk + e) * V + v];
        *(f16x8*)(Bt16 + (size_t)v * 256 + (k0 + kk)) = p;
    }
}

// ---------- K1: xg = embedding[x] @ W_ih + b    (B*T, 3H)
__global__ __launch_bounds__(384) void k1_embed_xg(const int* __restrict__ x,
                                                   const float* __restrict__ emb,
                                                   const float* __restrict__ W_ih,
                                                   const float* __restrict__ bias,
                                                   float* __restrict__ xg)
{
    int j = threadIdx.x;
    float w[E];
    #pragma unroll
    for (int k = 0; k < E; ++k) w[k] = W_ih[k * G3 + j];
    float bj = bias[j];

    __shared__ __align__(16) float erow[16][E];
    int row0 = blockIdx.x * 16;
    for (int i = j; i < 16 * E; i += G3) {
        int r = i >> 7, c = i & (E - 1);
        erow[r][c] = emb[(size_t)x[row0 + r] * E + c];
    }
    __syncthreads();
    for (int r = 0; r < 16; ++r) {
        float acc = bj;
        #pragma unroll
        for (int k = 0; k < E; k += 4) {
            f32x4 hv = *(const f32x4*)&erow[r][k];
            acc += hv[0]*w[k] + hv[1]*w[k+1] + hv[2]*w[k+2] + hv[3]*w[k+3];
        }
        xg[(size_t)(row0 + r) * G3 + j] = acc;
    }
}

// ---------- K2: GRU scan. One block per batch; W_hh column j in registers of thread j.
__global__ __launch_bounds__(384) void k2_gru(const float* __restrict__ xg,
                                              const float* __restrict__ W_hh,
                                              float* __restrict__ hs,
                                              f16* __restrict__ A16)
{
    int b = blockIdx.x;
    int j = threadIdx.x;
    float w[H];
    #pragma unroll
    for (int k = 0; k < H; ++k) w[k] = W_hh[k * G3 + j];

    __shared__ __align__(16) float h[H];
    __shared__ float g[G3];
    if (j < H) h[j] = 0.0f;
    __syncthreads();

    const float* xgb = xg + (size_t)b * T * G3;
    float xnext = xgb[j];
    for (int t = 0; t < T; ++t) {
        float acc = xnext;
        if (t + 1 < T) xnext = xgb[(size_t)(t + 1) * G3 + j];  // prefetch next step
        #pragma unroll
        for (int k = 0; k < H; k += 4) {
            f32x4 hv = *(const f32x4*)&h[k];
            acc += hv[0]*w[k] + hv[1]*w[k+1] + hv[2]*w[k+2] + hv[3]*w[k+3];
        }
        g[j] = acc;
        __syncthreads();
        if (j < H) {
            float z  = 1.0f / (1.0f + __expf(-g[j]));
            float r  = 1.0f / (1.0f + __expf(-g[H + j]));
            float pn = g[2 * H + j] * r;
            float ex = __expf(2.0f * pn);
            float n  = 1.0f - 2.0f / (ex + 1.0f);      // tanh(pn)
            float hn = (1.0f - z) * n + z * h[j];
            h[j] = hn;
            size_t bt = (size_t)b * T + t;
            hs[bt * H + j] = hn;
            A16[bt * 256 + j] = (f16)hn;               // first half of combined
        }
        __syncthreads();
    }
}

// ---------- K3: scores = tanh(hs @ attn_w + attn_b) @ v_w + v_b   (B*T,)
__global__ __launch_bounds__(128) void k3_scores(const float* __restrict__ hs,
                                                 const float* __restrict__ attn_w,
                                                 const float* __restrict__ attn_b,
                                                 const float* __restrict__ v_w,
                                                 const float* __restrict__ v_b,
                                                 float* __restrict__ scores)
{
    int i = threadIdx.x;
    float w[H];
    #pragma unroll
    for (int k = 0; k < H; ++k) w[k] = attn_w[k * H + i];
    float ab = attn_b[i];
    float vw = v_w[i];
    float vb = v_b[0];

    __shared__ __align__(16) float hrow[H];
    __shared__ float part[2];
    int row0 = blockIdx.x * 16;
    for (int r = 0; r < 16; ++r) {
        hrow[i] = hs[(size_t)(row0 + r) * H + i];
        __syncthreads();
        float acc = ab;
        #pragma unroll
        for (int k = 0; k < H; k += 4) {
            f32x4 hv = *(const f32x4*)&hrow[k];
            acc += hv[0]*w[k] + hv[1]*w[k+1] + hv[2]*w[k+2] + hv[3]*w[k+3];
        }
        float ex = __expf(2.0f * acc);
        float u  = (1.0f - 2.0f / (ex + 1.0f)) * vw;   // tanh(acc)*v_w[i]
        #pragma unroll
        for (int o = 32; o > 0; o >>= 1) u += __shfl_xor(u, o);
        if ((i & 63) == 0) part[i >> 6] = u;
        __syncthreads();
        if (i == 0) scores[row0 + r] = part[0] + part[1] + vb;
        __syncthreads();
    }
}

// ---------- K4: causal softmax over scores[s<t] and context; writes second half of A16.
__global__ __launch_bounds__(128) void k4_context(const float* __restrict__ hs,
                                                  const float* __restrict__ scores,
                                                  f16* __restrict__ A16)
{
    int bt = blockIdx.x;
    int b  = bt >> 7;
    int t  = bt & (T - 1);
    int i  = threadIdx.x;

    __shared__ float wts[T];
    __shared__ float redm[2], reds[2];
    const float* sc = scores + b * T;

    float sv = (i < t) ? sc[i] : -3.0e38f;
    float m = sv;
    #pragma unroll
    for (int o = 32; o > 0; o >>= 1) m = fmaxf(m, __shfl_xor(m, o));
    if ((i & 63) == 0) redm[i >> 6] = m;
    __syncthreads();
    m = fmaxf(redm[0], redm[1]);

    float ev = (i < t) ? __expf(sc[i] - m) : 0.0f;
    float s = ev;
    #pragma unroll
    for (int o = 32; o > 0; o >>= 1) s += __shfl_xor(s, o);
    if ((i & 63) == 0) reds[i >> 6] = s;
    __syncthreads();
    s = reds[0] + reds[1];

    float inv = (t > 0) ? 1.0f / s : 0.0f;   // t==0 -> context 0
    wts[i] = ev * inv;
    __syncthreads();

    float ctx = 0.0f;
    const float* hsb = hs + (size_t)b * T * H + i;
    for (int sI = 0; sI < t; ++sI)
        ctx = fmaf(wts[sI], hsb[(size_t)sI * H], ctx);

    A16[(size_t)bt * 256 + H + i] = (f16)ctx;
}

// ---------- K5: out = combined(4096x256) @ fc_w(256xV) + fc_b   via fp16 MFMA.
// Grid 16x16: block = (M-tile mi of 256 rows) x (N-group ni). A-tile lives in
// REGISTERS (loaded once -> immune to write-stream cache churn). Block ni
// processes chunks c = ni, ni+16, ... (128 cols each); each chunk staged once
// into a 2x64KB LDS double-buffer (global_load_lds, prefetch overlapped).
__global__ __launch_bounds__(512, 1) void k5_gemm(const f16* __restrict__ A16,
                                                  const f16* __restrict__ Bt16,
                                                  const float* __restrict__ fc_b,
                                                  float* __restrict__ out)
{
    __shared__ __align__(16) char Bs[2][65536];   // [buf][128 n][512 B k], XOR-swizzled
    int mi   = blockIdx.x;           // 0..15 M-tile (fast: same-ni blocks consecutive)
    int ni   = blockIdx.y;           // 0..15 N-group
    int tid  = threadIdx.x;
    int w    = tid >> 6;             // wave 0..7
    int lane = tid & 63;
    int l15  = lane & 15;
    int lhi  = lane >> 4;            // 0..3

    // ---- A fragments: loaded ONCE from global, persist in VGPRs (64/lane)
    const f16* Ab = A16 + (size_t)(mi * 256 + w * 32 + l15) * 256 + lhi * 8;
    f16x8 a[2][8];
    #pragma unroll
    for (int mf = 0; mf < 2; ++mf)
        #pragma unroll
        for (int kt = 0; kt < 8; ++kt)
            a[mf][kt] = *(const f16x8*)(Ab + mf * 16 * 256 + kt * 32);

    // ---- stage helper pattern: LDS[lin] = G[row][col ^ ((row&7)<<4)]
    // (done inline; 8 global_load_lds x 16B per thread = 64KB per block)
    {
        const char* src = (const char*)(Bt16 + (size_t)ni * 128 * 256);
        #pragma unroll
        for (int it = 0; it < 8; ++it) {
            int chunk = it * 8 + w;
            int lin   = chunk * 1024 + lane * 16;
            int row   = lin >> 9;
            int g     = lin ^ ((row & 7) << 4);
            __builtin_amdgcn_global_load_lds(
                (const __attribute__((address_space(1))) void*)(src + g),
                (__attribute__((address_space(3))) void*)(&Bs[0][0] + chunk * 1024),
                16, 0, 0);
        }
    }
    asm volatile("s_waitcnt vmcnt(0)");
    __syncthreads();

    int nc = (250 - ni + 15) >> 4;   // 16 (ni<10) or 15
    for (int j = 0; j < nc; ++j) {
        int c   = ni + j * 16;
        int cur = j & 1;

        // prefetch next chunk into the other buffer
        if (j + 1 < nc) {
            const char* src = (const char*)(Bt16 + (size_t)(c + 16) * 128 * 256);
            char* dst = &Bs[cur ^ 1][0];
            #pragma unroll
            for (int it = 0; it < 8; ++it) {
                int chunk = it * 8 + w;
                int lin   = chunk * 1024 + lane * 16;
                int row   = lin >> 9;
                int g     = lin ^ ((row & 7) << 4);
                __builtin_amdgcn_global_load_lds(
                    (const __attribute__((address_space(1))) void*)(src + g),
                    (__attribute__((address_space(3))) void*)(dst + chunk * 1024),
                    16, 0, 0);
            }
        }

        // acc initialized with bias (same for both mf)
        f32x4 acc[2][8];
        #pragma unroll
        for (int f = 0; f < 8; ++f) {
            f32x4 bv = *(const f32x4*)(fc_b + c * 128 + f * 16 + lhi * 4);
            acc[0][f] = bv;
            acc[1][f] = bv;
        }

        const char* bb = &Bs[cur][0];
        #pragma unroll
        for (int kt = 0; kt < 8; ++kt) {
            f16x8 bf[8];
            #pragma unroll
            for (int f = 0; f < 8; ++f) {
                int r  = f * 16 + l15;
                int ad = r * 512 + ((kt * 64 + lhi * 16) ^ ((r & 7) << 4));
                bf[f] = *(const f16x8*)(bb + ad);
            }
            #pragma unroll
            for (int mf = 0; mf < 2; ++mf)
                #pragma unroll
                for (int f = 0; f < 8; ++f)
                    acc[mf][f] = __builtin_amdgcn_mfma_f32_16x16x32_f16(bf[f], a[mf][kt], acc[mf][f], 0, 0, 0);
        }

        // stores: row = mi*256 + w*32 + mf*16 + l15, col = c*128 + f*16 + lhi*4
        #pragma unroll
        for (int f = 0; f < 8; ++f) {
            int col = c * 128 + f * 16 + lhi * 4;
            #pragma unroll
            for (int mf = 0; mf < 2; ++mf) {
                int row = mi * 256 + w * 32 + mf * 16 + l15;
                *(f32x4*)(out + (size_t)row * V + col) = acc[mf][f];
            }
        }

        asm volatile("s_waitcnt vmcnt(0)");   // prefetch (+stores) drained
        __syncthreads();                      // buffer swap safe
    }
}

extern "C" void kernel_launch(void* const* d_in, const int* in_sizes, int n_in,
                              void* d_out, int out_size, void* d_ws, size_t ws_size,
                              hipStream_t stream)
{
    (void)in_sizes; (void)n_in; (void)out_size; (void)ws_size;
    const int*   x      = (const int*)  d_in[0];
    const float* emb    = (const float*)d_in[1];
    const float* W_ih   = (const float*)d_in[2];
    const float* W_hh   = (const float*)d_in[3];
    const float* bias   = (const float*)d_in[4];
    const float* attn_w = (const float*)d_in[5];
    const float* attn_b = (const float*)d_in[6];
    const float* v_w    = (const float*)d_in[7];
    const float* v_b    = (const float*)d_in[8];
    const float* fc_w   = (const float*)d_in[9];
    const float* fc_b   = (const float*)d_in[10];
    float* out = (float*)d_out;

    char* ws = (char*)d_ws;
    float* xg     = (float*)(ws);              // 4096*384*4 = 6,291,456 B
    float* hs     = (float*)(ws + 6291456);    // 4096*128*4 = 2,097,152 B
    float* scores = (float*)(ws + 8388608);    // 4096*4     = 16,384 B
    f16*   A16    = (f16*)  (ws + 8404992);    // 4096*256*2 = 2,097,152 B
    f16*   Bt16   = (f16*)  (ws + 10502144);   // 32000*256*2 = 16,384,000 B

    hipLaunchKernelGGL(k0_convert_fcw, dim3(V / 256, 4), dim3(256), 0, stream, fc_w, Bt16);
    hipLaunchKernelGGL(k1_embed_xg,    dim3(B * T / 16), dim3(G3),  0, stream, x, emb, W_ih, bias, xg);
    hipLaunchKernelGGL(k2_gru,         dim3(B),          dim3(G3),  0, stream, xg, W_hh, hs, A16);
    hipLaunchKernelGGL(k3_scores,      dim3(B * T / 16), dim3(H),   0, stream, hs, attn_w, attn_b, v_w, v_b, scores);
    hipLaunchKernelGGL(k4_context,     dim3(B * T),      dim3(H),   0, stream, hs, scores, A16);
    hipLaunchKernelGGL(k5_gemm,        dim3(16, 16),     dim3(512), 0, stream, A16, Bt16, fc_b, out);
}